// Round 7
// baseline (11239.595 us; speedup 1.0000x reference)
//
#include <hip/hip_runtime.h>
#include <hip/hip_bf16.h>

#define NB 32
#define NT 512
#define NH 1024
#define G3 3072
#define NWG 128
#define LDS_BLOB 98304
#define LDS_PART 32768              // [2][4waves][4acc][64lane][4] f32, double-buffered
#define LDS_HLOC 2048
#define PK_LDS (LDS_BLOB + LDS_PART + LDS_HLOC)

typedef __attribute__((ext_vector_type(8))) short short8;
typedef __attribute__((ext_vector_type(4))) float f32x4;
typedef __attribute__((ext_vector_type(4))) unsigned short us4;
typedef unsigned long long u64;

static __device__ __forceinline__ unsigned short f2bf(float f) {
    union { float f; unsigned u; } v; v.f = f;
    if ((v.u & 0x7fffffffu) > 0x7f800000u) return (unsigned short)((v.u >> 16) | 0x0040u);
    unsigned u = v.u + 0x7fffu + ((v.u >> 16) & 1u);
    return (unsigned short)(u >> 16);
}

static __device__ __forceinline__ void coh_store8(u64* p, u64 v) {
    __hip_atomic_store(p, v, __ATOMIC_RELAXED, __HIP_MEMORY_SCOPE_AGENT);
}

// issue 16 coherent (L1/L2-bypassing) 16B loads at stride 64B; NO wait.
static __device__ __forceinline__ void coh_issue16(const char* base, short8 o[16]) {
    asm volatile(
        "global_load_dwordx4 %0,  %16, off sc0 sc1\n\t"
        "global_load_dwordx4 %1,  %16, off offset:64 sc0 sc1\n\t"
        "global_load_dwordx4 %2,  %16, off offset:128 sc0 sc1\n\t"
        "global_load_dwordx4 %3,  %16, off offset:192 sc0 sc1\n\t"
        "global_load_dwordx4 %4,  %16, off offset:256 sc0 sc1\n\t"
        "global_load_dwordx4 %5,  %16, off offset:320 sc0 sc1\n\t"
        "global_load_dwordx4 %6,  %16, off offset:384 sc0 sc1\n\t"
        "global_load_dwordx4 %7,  %16, off offset:448 sc0 sc1\n\t"
        "global_load_dwordx4 %8,  %16, off offset:512 sc0 sc1\n\t"
        "global_load_dwordx4 %9,  %16, off offset:576 sc0 sc1\n\t"
        "global_load_dwordx4 %10, %16, off offset:640 sc0 sc1\n\t"
        "global_load_dwordx4 %11, %16, off offset:704 sc0 sc1\n\t"
        "global_load_dwordx4 %12, %16, off offset:768 sc0 sc1\n\t"
        "global_load_dwordx4 %13, %16, off offset:832 sc0 sc1\n\t"
        "global_load_dwordx4 %14, %16, off offset:896 sc0 sc1\n\t"
        "global_load_dwordx4 %15, %16, off offset:960 sc0 sc1"
        : "=&v"(o[0]), "=&v"(o[1]), "=&v"(o[2]), "=&v"(o[3]),
          "=&v"(o[4]), "=&v"(o[5]), "=&v"(o[6]), "=&v"(o[7]),
          "=&v"(o[8]), "=&v"(o[9]), "=&v"(o[10]), "=&v"(o[11]),
          "=&v"(o[12]), "=&v"(o[13]), "=&v"(o[14]), "=&v"(o[15])
        : "v"(base)
        : "memory");
}

// wait + BIND the 16 loaded tuples so consumers cannot hoist above the wait
#define VMWAIT_BIND(NSTR, o)                                                   \
    asm volatile("s_waitcnt vmcnt(" NSTR ")"                                   \
        : "+v"(o[0]), "+v"(o[1]), "+v"(o[2]), "+v"(o[3]),                      \
          "+v"(o[4]), "+v"(o[5]), "+v"(o[6]), "+v"(o[7]),                      \
          "+v"(o[8]), "+v"(o[9]), "+v"(o[10]), "+v"(o[11]),                    \
          "+v"(o[12]), "+v"(o[13]), "+v"(o[14]), "+v"(o[15]) :: "memory");     \
    __builtin_amdgcn_sched_barrier(0)

// ---------------- f32 -> bf16 conversion (vectorized) ----------------
__global__ __launch_bounds__(256) void cvt_bf16_v4(const float4* __restrict__ src,
                                                   us4* __restrict__ dst, int n4) {
    for (int i = blockIdx.x * 256 + threadIdx.x; i < n4; i += gridDim.x * 256) {
        float4 v = src[i];
        us4 o;
        o.x = f2bf(v.x); o.y = f2bf(v.y); o.z = f2bf(v.z); o.w = f2bf(v.w);
        dst[i] = o;
    }
}

// ---------------- x [B][T][D] f32 -> xt [T][B][D] bf16 ----------------
__global__ __launch_bounds__(256) void txp_x(const float4* __restrict__ x, us4* __restrict__ xt) {
    const int total = NT * NB * 256;   // in float4 units
    for (int i = blockIdx.x * 256 + threadIdx.x; i < total; i += gridDim.x * 256) {
        int b = i / (NT * 256);
        int rem = i - b * (NT * 256);
        int t = rem >> 8;
        int d4 = rem & 255;
        float4 v = x[i];
        us4 o;
        o.x = f2bf(v.x); o.y = f2bf(v.y); o.z = f2bf(v.z); o.w = f2bf(v.w);
        xt[((size_t)t * NB + b) * 256 + d4] = o;
    }
}

// ---------------- init hidden bf16 shadows ----------------
__global__ __launch_bounds__(256) void init_h(const float* __restrict__ hid,
                                              unsigned short* __restrict__ h0b,
                                              unsigned short* __restrict__ h1b) {
    int i = blockIdx.x * 256 + threadIdx.x;   // grid covers exactly NB*NH
    h0b[i] = f2bf(hid[i]);
    h1b[i] = f2bf(hid[NB * NH + i]);
}

// ---------------- persistent 2-layer GRU ----------------
// flags layout: [layer][half][64] ints (half = batch 0-15 / 16-31).
// One __syncthreads per step; part[] double-buffered by step parity.
__global__ __launch_bounds__(256, 1) void gru_persistent(
    const unsigned short* __restrict__ xt,      // [T][B][1024] bf16
    unsigned short* __restrict__ y0b,           // [T][B][1024] bf16 (coherent)
    const unsigned short* __restrict__ wih0, const unsigned short* __restrict__ whh0,
    const unsigned short* __restrict__ wih1, const unsigned short* __restrict__ whh1,
    const float* __restrict__ bih0, const float* __restrict__ bhh0,
    const float* __restrict__ bih1, const float* __restrict__ bhh1,
    const float* __restrict__ hid,              // [2][B][1024] f32
    unsigned short* __restrict__ hb00, unsigned short* __restrict__ hb01,
    unsigned short* __restrict__ hb10, unsigned short* __restrict__ hb11,
    float* __restrict__ out,                    // y1 [B][T][1024] f32, then h [2][B][1024]
    int* __restrict__ flags)
{
    extern __shared__ char lds[];
    short* blob = (short*)lds;                               // w_hh fragment blobs
    float* part = (float*)(lds + LDS_BLOB);                  // 2x per-wave partials
    float* hloc = (float*)(lds + LDS_BLOB + LDS_PART);       // f32 h_prev [32][16]

    const int tid  = threadIdx.x;
    const int lane = tid & 63;
    const int wv   = tid >> 6;      // 0..3
    const int kh   = wv & 1;        // K-half
    const int mt   = wv >> 1;       // M-tile (batch 0-15 / 16-31)
    const int lr   = lane & 15;
    const int lq   = lane >> 4;

    const int wg   = blockIdx.x;
    const int lay  = wg >> 6;
    const int slot = wg & 63;
    const int j0   = slot * 16;

    const int* poll_own = flags + lay * 128 + mt * 64 + lane;
    const int* poll_y0  = flags + mt * 64 + lane;              // layer-0 flags
    int* pub = flags + lay * 128 + (tid >> 6) * 64 + slot;     // valid for wv 0/1

    const unsigned short* wih = lay ? wih1 : wih0;
    const unsigned short* whh = lay ? whh1 : whh0;
    const float* bih = lay ? bih1 : bih0;
    const float* bhh = lay ? bhh1 : bhh0;
    unsigned short* hb[2];
    if (lay == 0) { hb[0] = hb00; hb[1] = hb01; }
    else          { hb[0] = hb10; hb[1] = hb11; }

    // ---- stage w_hh rows {g*1024+j0 .. +16} into LDS, fragment-blob order ----
    for (int c = tid; c < 6144; c += 256) {
        int g   = c >> 11;
        int rem = c & 2047;
        int kt  = rem >> 6;
        int q   = (rem >> 4) & 3;
        int col = rem & 15;
        *(short8*)(blob + c * 8) =
            *(const short8*)((const short*)whh + (size_t)(g * 1024 + j0 + col) * 1024 + kt * 32 + q * 8);
    }

    // ---- per-thread gate constants + local f32 h init (threads 0..127: 4 cols each) ----
    float br_[4], bz_[4], bxn_[4], bhn_[4];
    if (tid < 128) {
        const int b = tid >> 2, c4 = (tid & 3) * 4;
#pragma unroll
        for (int j = 0; j < 4; ++j) {
            int gc = j0 + c4 + j;
            br_[j]  = bih[gc] + bhh[gc];
            bz_[j]  = bih[1024 + gc] + bhh[1024 + gc];
            bxn_[j] = bih[2048 + gc];
            bhn_[j] = bhh[2048 + gc];
        }
        float4 h0 = *(const float4*)&hid[(size_t)lay * NB * NH + (size_t)b * 1024 + j0 + c4];
        *(float4*)&hloc[b * 16 + c4] = h0;
    }
    __syncthreads();

    const int aoff = (mt * 16 + lr) * 1024 + lq * 8;             // element offset into [32][1024] slab
    const size_t aoff_b = (size_t)aoff * 2 + (size_t)kh * 1024;  // byte offset incl. K-half
    const short* wiB = (const short*)wih + (size_t)(j0 + lr) * 1024 + lq * 8;

    for (int t = 0; t < NT; ++t) {
        f32x4 acc0 = {0.f,0.f,0.f,0.f};   // r (proj+rec)
        f32x4 acc1 = {0.f,0.f,0.f,0.f};   // z (proj+rec)
        f32x4 acc2 = {0.f,0.f,0.f,0.f};   // n proj only
        f32x4 acc3 = {0.f,0.f,0.f,0.f};   // n rec only
        short8 ha[16];

        if (lay == 0) {
            // poll peers' h_t, then fly the h loads under the proj MFMAs
            while (__hip_atomic_load(poll_own, __ATOMIC_RELAXED, __HIP_MEMORY_SCOPE_AGENT) < t)
                __builtin_amdgcn_s_sleep(4);
            asm volatile("" ::: "memory");
            coh_issue16((const char*)hb[t & 1] + aoff_b, ha);

            const short* Ap = (const short*)xt + (size_t)t * NB * 1024 + aoff;
#pragma unroll 8
            for (int kk = 0; kk < 16; ++kk) {
                const int kt = kh * 16 + kk;
                short8 a  = *(const short8*)(Ap + kt * 32);
                short8 b0 = *(const short8*)(wiB + kt * 32);
                short8 b1 = *(const short8*)(wiB + 1024 * 1024 + kt * 32);
                short8 b2 = *(const short8*)(wiB + 2 * 1024 * 1024 + kt * 32);
                acc0 = __builtin_amdgcn_mfma_f32_16x16x32_bf16(a, b0, acc0, 0, 0, 0);
                acc1 = __builtin_amdgcn_mfma_f32_16x16x32_bf16(a, b1, acc1, 0, 0, 0);
                acc2 = __builtin_amdgcn_mfma_f32_16x16x32_bf16(a, b2, acc2, 0, 0, 0);
            }
            VMWAIT_BIND("0", ha);
        } else {
            // fused poll: y0[t] published AND peers' h_t published
            while (true) {
                int a  = __hip_atomic_load(poll_y0,  __ATOMIC_RELAXED, __HIP_MEMORY_SCOPE_AGENT);
                int b2 = __hip_atomic_load(poll_own, __ATOMIC_RELAXED, __HIP_MEMORY_SCOPE_AGENT);
                if (a >= t + 1 && b2 >= t) break;
                __builtin_amdgcn_s_sleep(4);
            }
            asm volatile("" ::: "memory");
            short8 ya[16];
            coh_issue16((const char*)y0b + (size_t)t * NB * 1024 * 2 + aoff_b, ya);
            coh_issue16((const char*)hb[t & 1] + aoff_b, ha);
            VMWAIT_BIND("16", ya);   // y0 (oldest 16) complete; h still in flight
#pragma unroll 8
            for (int kk = 0; kk < 16; ++kk) {
                const int kt = kh * 16 + kk;
                short8 b0 = *(const short8*)(wiB + kt * 32);
                short8 b1 = *(const short8*)(wiB + 1024 * 1024 + kt * 32);
                short8 b2 = *(const short8*)(wiB + 2 * 1024 * 1024 + kt * 32);
                acc0 = __builtin_amdgcn_mfma_f32_16x16x32_bf16(ya[kk], b0, acc0, 0, 0, 0);
                acc1 = __builtin_amdgcn_mfma_f32_16x16x32_bf16(ya[kk], b1, acc1, 0, 0, 0);
                acc2 = __builtin_amdgcn_mfma_f32_16x16x32_bf16(ya[kk], b2, acc2, 0, 0, 0);
            }
            VMWAIT_BIND("0", ha);
        }

        // ---- recurrent phase ----
#pragma unroll 8
        for (int kk = 0; kk < 16; ++kk) {
            const int kt = kh * 16 + kk;
            short8 c0 = *(const short8*)(blob + kt * 512 + lane * 8);
            short8 c1 = *(const short8*)(blob + (32 + kt) * 512 + lane * 8);
            short8 c2 = *(const short8*)(blob + (64 + kt) * 512 + lane * 8);
            acc0 = __builtin_amdgcn_mfma_f32_16x16x32_bf16(ha[kk], c0, acc0, 0, 0, 0);
            acc1 = __builtin_amdgcn_mfma_f32_16x16x32_bf16(ha[kk], c1, acc1, 0, 0, 0);
            acc3 = __builtin_amdgcn_mfma_f32_16x16x32_bf16(ha[kk], c2, acc3, 0, 0, 0);
        }

        float* pt = part + (t & 1) * 4096;
        *(f32x4*)(pt + ((wv * 4 + 0) * 64 + lane) * 4) = acc0;
        *(f32x4*)(pt + ((wv * 4 + 1) * 64 + lane) * 4) = acc1;
        *(f32x4*)(pt + ((wv * 4 + 2) * 64 + lane) * 4) = acc2;
        *(f32x4*)(pt + ((wv * 4 + 3) * 64 + lane) * 4) = acc3;
        __syncthreads();   // the ONLY per-step block barrier

        // ---- gates: waves 0/1, thread owns (b, 4 consecutive cols); reads partials direct ----
        if (tid < 128) {
            const int b = tid >> 2, c4 = (tid & 3) * 4;
            const int gc0 = j0 + c4;
            const int m = b >> 4, rg = b & 3, lq2 = (b >> 2) & 3;
            float hn[4];
            u64 hpack = 0;
#pragma unroll
            for (int j = 0; j < 4; ++j) {
                const int c = c4 + j;
                const int l = lq2 * 16 + c;
                const int i0 = ((m * 2 + 0) * 4) * 64 + l;
                const int i1 = ((m * 2 + 1) * 4) * 64 + l;
                float pr  = pt[(i0 + 0 * 64) * 4 + rg] + pt[(i1 + 0 * 64) * 4 + rg];
                float pz  = pt[(i0 + 1 * 64) * 4 + rg] + pt[(i1 + 1 * 64) * 4 + rg];
                float pxn = pt[(i0 + 2 * 64) * 4 + rg] + pt[(i1 + 2 * 64) * 4 + rg];
                float phn = pt[(i0 + 3 * 64) * 4 + rg] + pt[(i1 + 3 * 64) * 4 + rg];
                float r = 1.f / (1.f + __expf(-(pr + br_[j])));
                float z = 1.f / (1.f + __expf(-(pz + bz_[j])));
                float na = pxn + bxn_[j] + r * (phn + bhn_[j]);
                float e2 = __expf(-2.f * na);
                float n = (1.f - e2) / (1.f + e2);      // tanh(na)
                float hprev = hloc[b * 16 + c];
                float h = (1.f - z) * n + z * hprev;
                hloc[b * 16 + c] = h;
                hn[j] = h;
                hpack |= (u64)f2bf(h) << (16 * j);
            }
            coh_store8((u64*)((unsigned short*)hb[(t + 1) & 1] + (size_t)b * 1024 + gc0), hpack);
            if (lay == 0)
                coh_store8((u64*)(y0b + ((size_t)t * NB + b) * 1024 + gc0), hpack);

            // per-wave drain of the coherent stores, then publish this half's flag
            asm volatile("s_waitcnt vmcnt(0)" ::: "memory");
            if ((tid & 63) == 0)
                __hip_atomic_store(pub, t + 1, __ATOMIC_RELAXED, __HIP_MEMORY_SCOPE_AGENT);

            // non-consumed outputs AFTER the publish (off the critical path)
            if (lay == 1) {
                float4 o4; o4.x = hn[0]; o4.y = hn[1]; o4.z = hn[2]; o4.w = hn[3];
                *(float4*)&out[((size_t)b * NT + t) * 1024 + gc0] = o4;
            }
            if (t == NT - 1) {
                float4 o4; o4.x = hn[0]; o4.y = hn[1]; o4.z = hn[2]; o4.w = hn[3];
                *(float4*)&out[(size_t)NB * NT * 1024 + (size_t)lay * NB * NH + (size_t)b * 1024 + gc0] = o4;
            }
        }
    }
}

extern "C" void kernel_launch(void* const* d_in, const int* in_sizes, int n_in,
                              void* d_out, int out_size, void* d_ws, size_t ws_size,
                              hipStream_t stream) {
    (void)in_sizes; (void)n_in; (void)out_size; (void)ws_size;

    const float* x     = (const float*)d_in[0];
    const float* hid   = (const float*)d_in[1];
    const float* w_ih0 = (const float*)d_in[2];
    const float* w_hh0 = (const float*)d_in[3];
    const float* b_ih0 = (const float*)d_in[4];
    const float* b_hh0 = (const float*)d_in[5];
    const float* w_ih1 = (const float*)d_in[6];
    const float* w_hh1 = (const float*)d_in[7];
    const float* b_ih1 = (const float*)d_in[8];
    const float* b_hh1 = (const float*)d_in[9];
    float* out = (float*)d_out;

    char* ws = (char*)d_ws;
    size_t off = 0;
    auto alloc = [&](size_t bytes) -> void* {
        void* p = ws + off;
        off += (bytes + 255) & ~(size_t)255;
        return p;
    };

    unsigned short* xtb   = (unsigned short*)alloc((size_t)NT * NB * 1024 * 2);
    unsigned short* y0b   = (unsigned short*)alloc((size_t)NT * NB * 1024 * 2);
    unsigned short* wih0b = (unsigned short*)alloc((size_t)G3 * 1024 * 2);
    unsigned short* whh0b = (unsigned short*)alloc((size_t)G3 * 1024 * 2);
    unsigned short* wih1b = (unsigned short*)alloc((size_t)G3 * 1024 * 2);
    unsigned short* whh1b = (unsigned short*)alloc((size_t)G3 * 1024 * 2);
    unsigned short* hb0[2]; unsigned short* hb1[2];
    for (int i = 0; i < 2; i++) hb0[i] = (unsigned short*)alloc(NB * NH * 2);
    for (int i = 0; i < 2; i++) hb1[i] = (unsigned short*)alloc(NB * NH * 2);
    int* flags = (int*)alloc(2 * 2 * 64 * sizeof(int));   // packed: [layer][half][64]

    // --- conversions / init ---
    txp_x<<<2048, 256, 0, stream>>>((const float4*)x, (us4*)xtb);
    cvt_bf16_v4<<<512, 256, 0, stream>>>((const float4*)w_ih0, (us4*)wih0b, G3 * 1024 / 4);
    cvt_bf16_v4<<<512, 256, 0, stream>>>((const float4*)w_hh0, (us4*)whh0b, G3 * 1024 / 4);
    cvt_bf16_v4<<<512, 256, 0, stream>>>((const float4*)w_ih1, (us4*)wih1b, G3 * 1024 / 4);
    cvt_bf16_v4<<<512, 256, 0, stream>>>((const float4*)w_hh1, (us4*)whh1b, G3 * 1024 / 4);
    init_h<<<NB * NH / 256, 256, 0, stream>>>(hid, hb0[0], hb1[0]);
    hipMemsetAsync(flags, 0, 2 * 2 * 64 * sizeof(int), stream);

    // --- persistent recurrence (both layers, wavefront-pipelined) ---
    (void)hipFuncSetAttribute((const void*)gru_persistent,
                              hipFuncAttributeMaxDynamicSharedMemorySize, PK_LDS);
    gru_persistent<<<NWG, 256, PK_LDS, stream>>>(
        xtb, y0b, wih0b, whh0b, wih1b, whh1b,
        b_ih0, b_hh0, b_ih1, b_hh1, hid,
        hb0[0], hb0[1], hb1[0], hb1[1],
        out, flags);
}

// Round 8
// 8000.945 us; speedup vs baseline: 1.4048x; 1.4048x over previous
//
#include <hip/hip_runtime.h>
#include <hip/hip_bf16.h>

#define NB 32
#define NT 512
#define NH 1024
#define G3 3072
#define NWG 128
#define PK_LDS 98304   // w_hh fragment blob only

typedef __attribute__((ext_vector_type(8))) short short8;
typedef __attribute__((ext_vector_type(4))) float f32x4;
typedef __attribute__((ext_vector_type(4))) unsigned short us4;
typedef unsigned long long u64;

static __device__ __forceinline__ unsigned short f2bf(float f) {
    union { float f; unsigned u; } v; v.f = f;
    if ((v.u & 0x7fffffffu) > 0x7f800000u) return (unsigned short)((v.u >> 16) | 0x0040u);
    unsigned u = v.u + 0x7fffu + ((v.u >> 16) & 1u);
    return (unsigned short)(u >> 16);
}

static __device__ __forceinline__ void coh_store8(u64* p, u64 v) {
    __hip_atomic_store(p, v, __ATOMIC_RELAXED, __HIP_MEMORY_SCOPE_AGENT);
}

// issue 16 coherent (L1/L2-bypassing) 16B loads at stride 64B; NO wait.
static __device__ __forceinline__ void coh_issue16(const char* base, short8 o[16]) {
    asm volatile(
        "global_load_dwordx4 %0,  %16, off sc0 sc1\n\t"
        "global_load_dwordx4 %1,  %16, off offset:64 sc0 sc1\n\t"
        "global_load_dwordx4 %2,  %16, off offset:128 sc0 sc1\n\t"
        "global_load_dwordx4 %3,  %16, off offset:192 sc0 sc1\n\t"
        "global_load_dwordx4 %4,  %16, off offset:256 sc0 sc1\n\t"
        "global_load_dwordx4 %5,  %16, off offset:320 sc0 sc1\n\t"
        "global_load_dwordx4 %6,  %16, off offset:384 sc0 sc1\n\t"
        "global_load_dwordx4 %7,  %16, off offset:448 sc0 sc1\n\t"
        "global_load_dwordx4 %8,  %16, off offset:512 sc0 sc1\n\t"
        "global_load_dwordx4 %9,  %16, off offset:576 sc0 sc1\n\t"
        "global_load_dwordx4 %10, %16, off offset:640 sc0 sc1\n\t"
        "global_load_dwordx4 %11, %16, off offset:704 sc0 sc1\n\t"
        "global_load_dwordx4 %12, %16, off offset:768 sc0 sc1\n\t"
        "global_load_dwordx4 %13, %16, off offset:832 sc0 sc1\n\t"
        "global_load_dwordx4 %14, %16, off offset:896 sc0 sc1\n\t"
        "global_load_dwordx4 %15, %16, off offset:960 sc0 sc1"
        : "=&v"(o[0]), "=&v"(o[1]), "=&v"(o[2]), "=&v"(o[3]),
          "=&v"(o[4]), "=&v"(o[5]), "=&v"(o[6]), "=&v"(o[7]),
          "=&v"(o[8]), "=&v"(o[9]), "=&v"(o[10]), "=&v"(o[11]),
          "=&v"(o[12]), "=&v"(o[13]), "=&v"(o[14]), "=&v"(o[15])
        : "v"(base)
        : "memory");
}

// wait + BIND the 16 loaded tuples so consumers cannot hoist above the wait
#define VMWAIT_BIND16(NSTR, o)                                                 \
    asm volatile("s_waitcnt vmcnt(" NSTR ")"                                   \
        : "+v"(o[0]), "+v"(o[1]), "+v"(o[2]), "+v"(o[3]),                      \
          "+v"(o[4]), "+v"(o[5]), "+v"(o[6]), "+v"(o[7]),                      \
          "+v"(o[8]), "+v"(o[9]), "+v"(o[10]), "+v"(o[11]),                    \
          "+v"(o[12]), "+v"(o[13]), "+v"(o[14]), "+v"(o[15]) :: "memory");     \
    __builtin_amdgcn_sched_barrier(0)

#define MFMA_BF16 __builtin_amdgcn_mfma_f32_16x16x32_bf16

// ---------------- f32 -> bf16 conversion (vectorized) ----------------
__global__ __launch_bounds__(256) void cvt_bf16_v4(const float4* __restrict__ src,
                                                   us4* __restrict__ dst, int n4) {
    for (int i = blockIdx.x * 256 + threadIdx.x; i < n4; i += gridDim.x * 256) {
        float4 v = src[i];
        us4 o;
        o.x = f2bf(v.x); o.y = f2bf(v.y); o.z = f2bf(v.z); o.w = f2bf(v.w);
        dst[i] = o;
    }
}

// ---------------- x [B][T][D] f32 -> xt [T][B][D] bf16 ----------------
__global__ __launch_bounds__(256) void txp_x(const float4* __restrict__ x, us4* __restrict__ xt) {
    const int total = NT * NB * 256;   // in float4 units
    for (int i = blockIdx.x * 256 + threadIdx.x; i < total; i += gridDim.x * 256) {
        int b = i / (NT * 256);
        int rem = i - b * (NT * 256);
        int t = rem >> 8;
        int d4 = rem & 255;
        float4 v = x[i];
        us4 o;
        o.x = f2bf(v.x); o.y = f2bf(v.y); o.z = f2bf(v.z); o.w = f2bf(v.w);
        xt[((size_t)t * NB + b) * 256 + d4] = o;
    }
}

// ---------------- init hidden bf16 shadows ----------------
__global__ __launch_bounds__(256) void init_h(const float* __restrict__ hid,
                                              unsigned short* __restrict__ h0b,
                                              unsigned short* __restrict__ h1b) {
    int i = blockIdx.x * 256 + threadIdx.x;   // grid covers exactly NB*NH
    h0b[i] = f2bf(hid[i]);
    h1b[i] = f2bf(hid[NB * NH + i]);
}

// ---------------- persistent 2-layer GRU, wave-autonomous ----------------
// 128 WGs x 128 thr. WG = (layer, 16-col slice). Wave = batch-half (bh).
// Wave owns (16 batches x 16 cols x full K): weights are the MFMA A-operand
// (D row = w-col, D col = batch), so gates + h store are wave-local.
// NO per-step __syncthreads. flags[layer][bh][slot] = t+1 when that wave
// published h_{t+1} (and, for layer 0, y0[t]).
__global__ __launch_bounds__(128, 1) void gru_persistent(
    const unsigned short* __restrict__ xt,      // [T][B][1024] bf16
    unsigned short* __restrict__ y0b,           // [T][B][1024] bf16 (coherent)
    const unsigned short* __restrict__ wih0, const unsigned short* __restrict__ whh0,
    const unsigned short* __restrict__ wih1, const unsigned short* __restrict__ whh1,
    const float* __restrict__ bih0, const float* __restrict__ bhh0,
    const float* __restrict__ bih1, const float* __restrict__ bhh1,
    const float* __restrict__ hid,              // [2][B][1024] f32
    unsigned short* __restrict__ hb00, unsigned short* __restrict__ hb01,
    unsigned short* __restrict__ hb10, unsigned short* __restrict__ hb11,
    float* __restrict__ out,                    // y1 [B][T][1024] f32, then h [2][B][1024]
    int* __restrict__ flags)
{
    extern __shared__ char lds[];
    short* blob = (short*)lds;   // w_hh A-fragment blob: 48 rows x 1024 K = 96 KB

    const int tid  = threadIdx.x;
    const int lane = tid & 63;
    const int bh   = tid >> 6;        // batch half 0/1
    const int lr   = lane & 15;       // batch-within-half (B) / w-row (A)
    const int lq   = lane >> 4;       // k-octet index

    const int wg    = blockIdx.x;
    const int lay   = wg >> 6;
    const int slot  = wg & 63;
    const int j0    = slot * 16;
    const int batch = bh * 16 + lr;
    const int colg  = lq * 4;         // D rows (lane>>4)*4+reg -> cols j0+colg..+3
    const int gc0   = j0 + colg;

    const int* poll_own = flags + lay * 128 + bh * 64 + lane;   // 64 slots, same bh
    const int* poll_y0  = flags + bh * 64 + lane;               // layer-0 flags, same bh
    int* pub = flags + lay * 128 + bh * 64 + slot;

    const unsigned short* wih = lay ? wih1 : wih0;
    const unsigned short* whh = lay ? whh1 : whh0;
    const float* bih = lay ? bih1 : bih0;
    const float* bhh = lay ? bhh1 : bhh0;
    unsigned short* hb[2];
    if (lay == 0) { hb[0] = hb00; hb[1] = hb01; }
    else          { hb[0] = hb10; hb[1] = hb11; }

    // ---- stage w_hh rows {g*1024+j0 .. +16} into LDS A-frag blob ----
    // chunk c = (g*32+kt)*64 + q*16 + col holds w[g*1024+j0+col][kt*32+q*8..+8]
    // read back as short8 at blob + (g*32+kt)*512 + lane*8  (row=lane&15, k-oct=lane>>4)
    for (int c = tid; c < 6144; c += 128) {
        int g   = c >> 11;
        int rem = c & 2047;
        int kt  = rem >> 6;
        int q   = (rem >> 4) & 3;
        int col = rem & 15;
        *(short8*)(blob + c * 8) =
            *(const short8*)((const short*)whh + (size_t)(g * 1024 + j0 + col) * 1024 + kt * 32 + q * 8);
    }

    // ---- per-lane gate constants + f32 master h in registers ----
    float br_[4], bz_[4], bxn_[4], bhn_[4];
#pragma unroll
    for (int j = 0; j < 4; ++j) {
        int gc = gc0 + j;
        br_[j]  = bih[gc] + bhh[gc];
        bz_[j]  = bih[1024 + gc] + bhh[1024 + gc];
        bxn_[j] = bih[2048 + gc];
        bhn_[j] = bhh[2048 + gc];
    }
    f32x4 hloc = *(const f32x4*)&hid[(size_t)lay * NB * NH + (size_t)batch * 1024 + gc0];

    __syncthreads();   // blob ready (the only block barrier in the kernel)

    const short* wiA = (const short*)wih + (size_t)(j0 + lr) * 1024 + lq * 8;

    for (int t = 0; t < NT; ++t) {
        f32x4 ar  = {0.f,0.f,0.f,0.f};   // r pre-act
        f32x4 az  = {0.f,0.f,0.f,0.f};   // z pre-act
        f32x4 axn = {0.f,0.f,0.f,0.f};   // n proj part
        f32x4 ahn = {0.f,0.f,0.f,0.f};   // n rec part

        // ---------- input projection (before own-h poll: overlaps peers' publish) ----------
        if (lay == 0) {
            const short* Ap = (const short*)xt + ((size_t)t * NB + batch) * 1024 + lq * 8;
#pragma unroll 8
            for (int kt = 0; kt < 32; ++kt) {
                short8 xb = *(const short8*)(Ap + kt * 32);
                short8 w0 = *(const short8*)(wiA + kt * 32);
                short8 w1 = *(const short8*)(wiA + 1048576 + kt * 32);
                short8 w2 = *(const short8*)(wiA + 2097152 + kt * 32);
                ar  = MFMA_BF16(w0, xb, ar, 0, 0, 0);
                az  = MFMA_BF16(w1, xb, az, 0, 0, 0);
                axn = MFMA_BF16(w2, xb, axn, 0, 0, 0);
            }
        } else {
            while (__hip_atomic_load(poll_y0, __ATOMIC_RELAXED, __HIP_MEMORY_SCOPE_AGENT) < t + 1)
                __builtin_amdgcn_s_sleep(2);
            asm volatile("" ::: "memory");
            short8 ya0[16], ya1[16];
            const char* yb = (const char*)y0b + (((size_t)t * NB + batch) * 1024 + lq * 8) * 2;
            coh_issue16(yb, ya0);
            coh_issue16(yb + 1024, ya1);
            VMWAIT_BIND16("16", ya0);
#pragma unroll
            for (int kt = 0; kt < 16; ++kt) {
                short8 w0 = *(const short8*)(wiA + kt * 32);
                short8 w1 = *(const short8*)(wiA + 1048576 + kt * 32);
                short8 w2 = *(const short8*)(wiA + 2097152 + kt * 32);
                ar  = MFMA_BF16(w0, ya0[kt], ar, 0, 0, 0);
                az  = MFMA_BF16(w1, ya0[kt], az, 0, 0, 0);
                axn = MFMA_BF16(w2, ya0[kt], axn, 0, 0, 0);
            }
            VMWAIT_BIND16("0", ya1);
#pragma unroll
            for (int kk = 0; kk < 16; ++kk) {
                const int kt = kk + 16;
                short8 w0 = *(const short8*)(wiA + kt * 32);
                short8 w1 = *(const short8*)(wiA + 1048576 + kt * 32);
                short8 w2 = *(const short8*)(wiA + 2097152 + kt * 32);
                ar  = MFMA_BF16(w0, ya1[kk], ar, 0, 0, 0);
                az  = MFMA_BF16(w1, ya1[kk], az, 0, 0, 0);
                axn = MFMA_BF16(w2, ya1[kk], axn, 0, 0, 0);
            }
        }

        // ---------- recurrent part ----------
        while (__hip_atomic_load(poll_own, __ATOMIC_RELAXED, __HIP_MEMORY_SCOPE_AGENT) < t)
            __builtin_amdgcn_s_sleep(2);
        asm volatile("" ::: "memory");
        {
            short8 ha0[16], ha1[16];
            const char* hbase = (const char*)hb[t & 1] + ((size_t)batch * 1024 + lq * 8) * 2;
            coh_issue16(hbase, ha0);
            coh_issue16(hbase + 1024, ha1);
            VMWAIT_BIND16("16", ha0);
#pragma unroll
            for (int kt = 0; kt < 16; ++kt) {
                short8 b0 = *(const short8*)(blob + kt * 512 + lane * 8);
                short8 b1 = *(const short8*)(blob + (32 + kt) * 512 + lane * 8);
                short8 b2 = *(const short8*)(blob + (64 + kt) * 512 + lane * 8);
                ar  = MFMA_BF16(b0, ha0[kt], ar, 0, 0, 0);
                az  = MFMA_BF16(b1, ha0[kt], az, 0, 0, 0);
                ahn = MFMA_BF16(b2, ha0[kt], ahn, 0, 0, 0);
            }
            VMWAIT_BIND16("0", ha1);
#pragma unroll
            for (int kk = 0; kk < 16; ++kk) {
                const int kt = kk + 16;
                short8 b0 = *(const short8*)(blob + kt * 512 + lane * 8);
                short8 b1 = *(const short8*)(blob + (32 + kt) * 512 + lane * 8);
                short8 b2 = *(const short8*)(blob + (64 + kt) * 512 + lane * 8);
                ar  = MFMA_BF16(b0, ha1[kk], ar, 0, 0, 0);
                az  = MFMA_BF16(b1, ha1[kk], az, 0, 0, 0);
                ahn = MFMA_BF16(b2, ha1[kk], ahn, 0, 0, 0);
            }
        }

        // ---------- gates (all wave-local: batch = lane&15, cols gc0..gc0+3) ----------
        u64 hpack = 0;
        float hv[4];
#pragma unroll
        for (int j = 0; j < 4; ++j) {
            float r  = 1.f / (1.f + __expf(-(ar[j] + br_[j])));
            float z  = 1.f / (1.f + __expf(-(az[j] + bz_[j])));
            float na = axn[j] + bxn_[j] + r * (ahn[j] + bhn_[j]);
            float e2 = __expf(-2.f * na);
            float n  = (1.f - e2) / (1.f + e2);      // tanh(na)
            float h  = (1.f - z) * n + z * hloc[j];
            hloc[j] = h;
            hv[j] = h;
            hpack |= (u64)f2bf(h) << (16 * j);
        }
        coh_store8((u64*)((unsigned short*)hb[(t + 1) & 1] + (size_t)batch * 1024 + gc0), hpack);
        if (lay == 0)
            coh_store8((u64*)(y0b + ((size_t)t * NB + batch) * 1024 + gc0), hpack);

        asm volatile("s_waitcnt vmcnt(0)" ::: "memory");   // drain to LLC
        if (lane == 0)
            __hip_atomic_store(pub, t + 1, __ATOMIC_RELAXED, __HIP_MEMORY_SCOPE_AGENT);

        // non-consumed outputs AFTER publish (off the critical path)
        if (lay == 1) {
            float4 o4; o4.x = hv[0]; o4.y = hv[1]; o4.z = hv[2]; o4.w = hv[3];
            *(float4*)&out[((size_t)batch * NT + t) * 1024 + gc0] = o4;
        }
        if (t == NT - 1) {
            float4 o4; o4.x = hv[0]; o4.y = hv[1]; o4.z = hv[2]; o4.w = hv[3];
            *(float4*)&out[(size_t)NB * NT * 1024 + (size_t)lay * NB * NH + (size_t)batch * 1024 + gc0] = o4;
        }
    }
}

extern "C" void kernel_launch(void* const* d_in, const int* in_sizes, int n_in,
                              void* d_out, int out_size, void* d_ws, size_t ws_size,
                              hipStream_t stream) {
    (void)in_sizes; (void)n_in; (void)out_size; (void)ws_size;

    const float* x     = (const float*)d_in[0];
    const float* hid   = (const float*)d_in[1];
    const float* w_ih0 = (const float*)d_in[2];
    const float* w_hh0 = (const float*)d_in[3];
    const float* b_ih0 = (const float*)d_in[4];
    const float* b_hh0 = (const float*)d_in[5];
    const float* w_ih1 = (const float*)d_in[6];
    const float* w_hh1 = (const float*)d_in[7];
    const float* b_ih1 = (const float*)d_in[8];
    const float* b_hh1 = (const float*)d_in[9];
    float* out = (float*)d_out;

    char* ws = (char*)d_ws;
    size_t off = 0;
    auto alloc = [&](size_t bytes) -> void* {
        void* p = ws + off;
        off += (bytes + 255) & ~(size_t)255;
        return p;
    };

    unsigned short* xtb   = (unsigned short*)alloc((size_t)NT * NB * 1024 * 2);
    unsigned short* y0b   = (unsigned short*)alloc((size_t)NT * NB * 1024 * 2);
    unsigned short* wih0b = (unsigned short*)alloc((size_t)G3 * 1024 * 2);
    unsigned short* whh0b = (unsigned short*)alloc((size_t)G3 * 1024 * 2);
    unsigned short* wih1b = (unsigned short*)alloc((size_t)G3 * 1024 * 2);
    unsigned short* whh1b = (unsigned short*)alloc((size_t)G3 * 1024 * 2);
    unsigned short* hb0[2]; unsigned short* hb1[2];
    for (int i = 0; i < 2; i++) hb0[i] = (unsigned short*)alloc(NB * NH * 2);
    for (int i = 0; i < 2; i++) hb1[i] = (unsigned short*)alloc(NB * NH * 2);
    int* flags = (int*)alloc(2 * 2 * 64 * sizeof(int));   // [layer][bh][64]

    // --- conversions / init ---
    txp_x<<<2048, 256, 0, stream>>>((const float4*)x, (us4*)xtb);
    cvt_bf16_v4<<<512, 256, 0, stream>>>((const float4*)w_ih0, (us4*)wih0b, G3 * 1024 / 4);
    cvt_bf16_v4<<<512, 256, 0, stream>>>((const float4*)w_hh0, (us4*)whh0b, G3 * 1024 / 4);
    cvt_bf16_v4<<<512, 256, 0, stream>>>((const float4*)w_ih1, (us4*)wih1b, G3 * 1024 / 4);
    cvt_bf16_v4<<<512, 256, 0, stream>>>((const float4*)w_hh1, (us4*)whh1b, G3 * 1024 / 4);
    init_h<<<NB * NH / 256, 256, 0, stream>>>(hid, hb0[0], hb1[0]);
    hipMemsetAsync(flags, 0, 2 * 2 * 64 * sizeof(int), stream);

    // --- persistent recurrence (both layers, wavefront-pipelined) ---
    (void)hipFuncSetAttribute((const void*)gru_persistent,
                              hipFuncAttributeMaxDynamicSharedMemorySize, PK_LDS);
    gru_persistent<<<NWG, 128, PK_LDS, stream>>>(
        xtb, y0b, wih0b, whh0b, wih1b, whh1b,
        b_ih0, b_hh0, b_ih1, b_hh1, hid,
        hb0[0], hb0[1], hb1[0], hb1[1],
        out, flags);
}